// Round 7
// baseline (1127.503 us; speedup 1.0000x reference)
//
#include <hip/hip_runtime.h>
#include <cstdint>

#define BATCH 4
#define NPTS  8192
#define KNN   5
#define GRID  32
#define NCELL (GRID * GRID * GRID)
#define NTILE 128          // 8192/64 tiles per batch

typedef short bf16x8 __attribute__((ext_vector_type(8)));
typedef float f32x4  __attribute__((ext_vector_type(4)));
#define MFMA16(a, b, c) __builtin_amdgcn_mfma_f32_16x16x32_bf16((a), (b), (c), 0, 0, 0)

__device__ __forceinline__ unsigned short f2bf(float x) {
    unsigned u = __float_as_uint(x);
    unsigned r = u + 0x7fffu + ((u >> 16) & 1u);   // RN-even
    return (unsigned short)(r >> 16);
}
__device__ __forceinline__ float bf2f(unsigned short h) {
    return __uint_as_float(((unsigned)h) << 16);
}

// monotone float <-> uint key (for atomic min/max)
__device__ __forceinline__ unsigned encf(float f) {
    int i = __float_as_int(f);
    return (unsigned)i ^ ((i >> 31) ? 0xFFFFFFFFu : 0x80000000u);
}
__device__ __forceinline__ float decf(unsigned k) {
    return __int_as_float((k & 0x80000000u) ? (int)(k ^ 0x80000000u) : (int)~k);
}

__device__ __forceinline__ int spread3(int v) {   // 5-bit -> every 3rd bit
    v &= 0x3ff;
    v = (v | (v << 16)) & 0x030000FF;
    v = (v | (v << 8))  & 0x0300F00F;
    v = (v | (v << 4))  & 0x030C30C3;
    v = (v | (v << 2))  & 0x09249249;
    return v;
}

// shared cell mapping (must be identical in count/scatter) -> MORTON code
__device__ __forceinline__ int cell_of(float px, float py, float pz,
                                       const float* __restrict__ bb) {
    const float ihx = (float)GRID / (bb[4] - bb[0]);
    const float ihy = (float)GRID / (bb[5] - bb[1]);
    const float ihz = (float)GRID / (bb[6] - bb[2]);
    const int cx = min(GRID - 1, max(0, (int)((px - bb[0]) * ihx)));
    const int cy = min(GRID - 1, max(0, (int)((py - bb[1]) * ihy)));
    const int cz = min(GRID - 1, max(0, (int)((pz - bb[2]) * ihz)));
    return spread3(cx) | (spread3(cy) << 1) | (spread3(cz) << 2);
}

__device__ __forceinline__ float rl(float v, int l) {
    return __int_as_float(__builtin_amdgcn_readlane(__float_as_int(v), l));
}
__device__ __forceinline__ float wmaxf(float v) {
    #pragma unroll
    for (int m = 1; m < 64; m <<= 1) v = fmaxf(v, __shfl_xor(v, m));
    return v;
}

// ---------------------------------------------------------------------------
// Kernel W: split w3/w4/w5 into bf16 hi/lo pairs (fp32-emulation operands).
// ---------------------------------------------------------------------------
__global__ __launch_bounds__(256) void wsplit_kernel(
        const float* __restrict__ w3, const float* __restrict__ w4,
        const float* __restrict__ w5,
        unsigned short* __restrict__ w3H, unsigned short* __restrict__ w3L,
        unsigned short* __restrict__ w4H, unsigned short* __restrict__ w4L,
        unsigned short* __restrict__ w5H, unsigned short* __restrict__ w5L) {
    const int i = blockIdx.x * 256 + threadIdx.x;   // 303104 total, exact grid
    const float* src; unsigned short *dh, *dl; int off;
    if (i < 8192)       { src = w3; dh = w3H; dl = w3L; off = i; }
    else if (i < 40960) { src = w4; dh = w4H; dl = w4L; off = i - 8192; }
    else                { src = w5; dh = w5H; dl = w5L; off = i - 40960; }
    const float v = src[off];
    const unsigned short hi = f2bf(v);
    dh[off] = hi;
    dl[off] = f2bf(v - bf2f(hi));
}

// ---------------------------------------------------------------------------
// KNN build 1: per-batch bbox (padded) + zero the cell counters.
// ---------------------------------------------------------------------------
__global__ __launch_bounds__(1024) void bbox_kernel(const float* __restrict__ x,
                                                    float* __restrict__ bboxF,
                                                    int* __restrict__ counts) {
    __shared__ unsigned mnmx[6];
    const int b = blockIdx.x, t = threadIdx.x;
    if (t < 3) { mnmx[t] = 0xFFFFFFFFu; mnmx[3 + t] = 0u; }
    __syncthreads();
    const float* xb = x + (size_t)b * 3 * NPTS;
    #pragma unroll
    for (int a = 0; a < 3; ++a) {
        float lo = 3e38f, hi = -3e38f;
        for (int j = t; j < NPTS; j += 1024) {
            const float f = xb[a * NPTS + j];
            lo = fminf(lo, f); hi = fmaxf(hi, f);
        }
        atomicMin(&mnmx[a], encf(lo));
        atomicMax(&mnmx[3 + a], encf(hi));
    }
    __syncthreads();
    if (t < 3) {
        bboxF[b * 8 + t]     = decf(mnmx[t]) - 1e-3f;
        bboxF[b * 8 + 4 + t] = decf(mnmx[3 + t]) + 1e-3f;
    }
    int* cb = counts + b * NCELL;
    for (int j = t; j < NCELL; j += 1024) cb[j] = 0;
}

// ---------------------------------------------------------------------------
// KNN build 2: histogram points into morton cells.
// ---------------------------------------------------------------------------
__global__ __launch_bounds__(256) void count_kernel(const float* __restrict__ x,
                                                    const float* __restrict__ bboxF,
                                                    int* __restrict__ counts) {
    const int i = blockIdx.x * 256 + threadIdx.x;
    const int b = i >> 13, n = i & (NPTS - 1);
    const float* xb = x + (size_t)b * 3 * NPTS;
    const int c = cell_of(xb[n], xb[NPTS + n], xb[2 * NPTS + n], bboxF + b * 8);
    atomicAdd(&counts[b * NCELL + c], 1);
}

// ---------------------------------------------------------------------------
// KNN build 3: exclusive prefix over 32768 cells per batch (1 block).
// ---------------------------------------------------------------------------
__global__ __launch_bounds__(1024) void prefix_kernel(const int* __restrict__ counts,
                                                      int* __restrict__ cell_cur) {
    __shared__ int ssum[1024];
    const int b = blockIdx.x, t = threadIdx.x;
    const int* cb = counts + b * NCELL;
    int loc[32];
    int s = 0;
    #pragma unroll
    for (int j = 0; j < 32; ++j) { loc[j] = s; s += cb[t * 32 + j]; }
    ssum[t] = s;
    __syncthreads();
    for (int off = 1; off < 1024; off <<= 1) {
        const int v = (t >= off) ? ssum[t - off] : 0;
        __syncthreads();
        ssum[t] += v;
        __syncthreads();
    }
    const int base = ssum[t] - s;          // exclusive
    int* oc = cell_cur + b * NCELL;
    #pragma unroll
    for (int j = 0; j < 32; ++j) oc[t * 32 + j] = base + loc[j];
}

// ---------------------------------------------------------------------------
// KNN build 4: scatter points into morton-sorted order (orig idx in .w).
// ---------------------------------------------------------------------------
__global__ __launch_bounds__(256) void scatter_kernel(const float* __restrict__ x,
                                                      const float* __restrict__ bboxF,
                                                      int* __restrict__ cell_cur,
                                                      float4* __restrict__ sorted) {
    const int i = blockIdx.x * 256 + threadIdx.x;
    const int b = i >> 13, n = i & (NPTS - 1);
    const float* xb = x + (size_t)b * 3 * NPTS;
    const float px = xb[n], py = xb[NPTS + n], pz = xb[2 * NPTS + n];
    const int c = cell_of(px, py, pz, bboxF + b * 8);
    const int slot = atomicAdd(&cell_cur[b * NCELL + c], 1);
    sorted[(size_t)b * NPTS + slot] = make_float4(px, py, pz, __int_as_float(n));
}

// ---------------------------------------------------------------------------
// KNN build 5: per-tile bbox (64 consecutive sorted points), one wave/tile.
// ---------------------------------------------------------------------------
__global__ __launch_bounds__(256) void tilebox_kernel(const float4* __restrict__ sorted,
                                                      float4* __restrict__ tboxLo,
                                                      float4* __restrict__ tboxHi) {
    const int t = threadIdx.x, lane = t & 63, w = t >> 6;
    const int tile = blockIdx.x * 4 + w;           // 0..511 (B*NTILE)
    const float4 p = sorted[(size_t)tile * 64 + lane];
    float lx = p.x, ly = p.y, lz = p.z, hx = p.x, hy = p.y, hz = p.z;
    #pragma unroll
    for (int m = 1; m < 64; m <<= 1) {
        lx = fminf(lx, __shfl_xor(lx, m)); hx = fmaxf(hx, __shfl_xor(hx, m));
        ly = fminf(ly, __shfl_xor(ly, m)); hy = fmaxf(hy, __shfl_xor(hy, m));
        lz = fminf(lz, __shfl_xor(lz, m)); hz = fmaxf(hz, __shfl_xor(hz, m));
    }
    if (lane == 0) {
        tboxLo[tile] = make_float4(lx, ly, lz, 0.f);
        tboxHi[tile] = make_float4(hx, hy, hz, 0.f);
    }
}

// ---------------------------------------------------------------------------
// KNN query: wave-coherent tile-pruned exact 5-NN.
// Wave g's 64 lanes ARE tile (g&127)'s 64 points (morton order) -> wave bbox
// == tile bbox. Sweep 1: expanding tile walk from own index; skip tile i if
// bboxLB^2 > waveMax(s4u) (wave-uniform); accepted tiles scanned via coalesced
// float4 load + v_readlane broadcast into dual branchless fmed3 top-5 chains.
// Sweep 2: re-check all tiles vs final T=s4u+1e-4, collect finalists (<=16).
// Phase 3: exact fp64 (d,idx)-lexicographic re-rank (top_k tie semantics).
// Exactness: skip margin 1e-4 >> fp32 dist/LB error (~2e-5); pruning during
// sweep 1 only makes s4u conservative (larger) -> safe.
// ---------------------------------------------------------------------------
__global__ __launch_bounds__(256) void knn_tile_kernel(
        const float* __restrict__ x, const float4* __restrict__ sorted,
        const float4* __restrict__ tboxLo, const float4* __restrict__ tboxHi,
        int* __restrict__ idx_out) {
    __shared__ int qidxL[256 * 16];
    const int t = threadIdx.x, lane = t & 63, w = t >> 6;
    const int g = blockIdx.x * 4 + w;      // 0..511
    const int b = g >> 7;
    const int t0 = g & (NTILE - 1);
    const float4* sp = sorted + (size_t)b * NPTS;
    const float4* tlo = tboxLo + (size_t)b * NTILE;
    const float4* thi = tboxHi + (size_t)b * NTILE;
    const float* xb = x + (size_t)b * 3 * NPTS;

    const float4 qp = sp[t0 * 64 + lane];
    const float qx = qp.x, qy = qp.y, qz = qp.z;
    const int nq = __float_as_int(qp.w);
    const float4 wlo = tlo[t0], whi = thi[t0];

    float a0 = 3e38f, a1 = 3e38f, a2 = 3e38f, a3 = 3e38f, a4 = 3e38f;
    float b0 = 3e38f, b1 = 3e38f, b2 = 3e38f, b3 = 3e38f, b4 = 3e38f;
    auto insA = [&](float d) {
        a4 = __builtin_amdgcn_fmed3f(a3, d, a4);
        a3 = __builtin_amdgcn_fmed3f(a2, d, a3);
        a2 = __builtin_amdgcn_fmed3f(a1, d, a2);
        a1 = __builtin_amdgcn_fmed3f(a0, d, a1);
        a0 = fminf(a0, d);
    };
    auto insB = [&](float d) {
        b4 = __builtin_amdgcn_fmed3f(b3, d, b4);
        b3 = __builtin_amdgcn_fmed3f(b2, d, b3);
        b2 = __builtin_amdgcn_fmed3f(b1, d, b2);
        b1 = __builtin_amdgcn_fmed3f(b0, d, b1);
        b0 = fminf(b0, d);
    };
    auto u5 = [&]() {   // 5th smallest of union of the two sorted chains
        return fminf(fminf(fminf(a4, b4), fminf(fmaxf(a0, b3), fmaxf(a1, b2))),
                     fminf(fmaxf(a2, b1), fmaxf(a3, b0)));
    };
    auto lb2 = [&](int i) -> float {   // bbox-to-bbox min dist^2 (wave-uniform)
        const float4 lo = tlo[i], hi = thi[i];
        const float dx = fmaxf(0.f, fmaxf(lo.x - whi.x, wlo.x - hi.x));
        const float dy = fmaxf(0.f, fmaxf(lo.y - whi.y, wlo.y - hi.y));
        const float dz = fmaxf(0.f, fmaxf(lo.z - whi.z, wlo.z - hi.z));
        return fmaf(dz, dz, fmaf(dy, dy, dx * dx));
    };
    auto scan1 = [&](int i) {
        const float4 cp = sp[i * 64 + lane];    // coalesced 1KB
        #pragma unroll 8
        for (int j = 0; j < 64; j += 2) {
            const float dx0 = qx - rl(cp.x, j),     dy0 = qy - rl(cp.y, j),     dz0 = qz - rl(cp.z, j);
            const float dx1 = qx - rl(cp.x, j + 1), dy1 = qy - rl(cp.y, j + 1), dz1 = qz - rl(cp.z, j + 1);
            insA(fmaf(dz0, dz0, fmaf(dy0, dy0, dx0 * dx0)));
            insB(fmaf(dz1, dz1, fmaf(dy1, dy1, dx1 * dx1)));
        }
    };

    // ---- sweep 1: expanding pruned scan ----
    scan1(t0);
    float thr = wmaxf(u5());
    for (int d = 1; d < NTILE; ++d) {
        const int i1 = t0 - d, i2 = t0 + d;
        if (i1 >= 0    && lb2(i1) <= thr) { scan1(i1); thr = wmaxf(u5()); }
        if (i2 < NTILE && lb2(i2) <= thr) { scan1(i2); thr = wmaxf(u5()); }
    }

    // ---- sweep 2: collect finalists vs tight threshold ----
    const float Tl = u5() + 1e-4f;
    const float thr2 = wmaxf(Tl);
    int cnt = 0;
    for (int i = 0; i < NTILE; ++i) {
        if (lb2(i) > thr2) continue;
        const float4 cp = sp[i * 64 + lane];
        #pragma unroll 8
        for (int j = 0; j < 64; ++j) {
            const float cx = rl(cp.x, j), cy = rl(cp.y, j), cz = rl(cp.z, j);
            const float dx = qx - cx, dy = qy - cy, dz = qz - cz;
            const float dd = fmaf(dz, dz, fmaf(dy, dy, dx * dx));
            if (dd < Tl) {
                if (cnt < 16) qidxL[t * 16 + cnt] = __builtin_amdgcn_readlane(
                        __float_as_int(cp.w), j);
                ++cnt;
            }
        }
    }
    cnt = min(cnt, 16);

    // ---- phase 3: exact fp64 lexicographic top-5 ----
    double d0 = 1e300, d1 = 1e300, d2 = 1e300, d3 = 1e300, d4 = 1e300;
    int i0 = 0x7fffffff, i1 = 0x7fffffff, i2 = 0x7fffffff, i3 = 0x7fffffff, i4 = 0x7fffffff;
    const double Qx = (double)qx, Qy = (double)qy, Qz = (double)qz;
    for (int j = 0; j < cnt; ++j) {
        const int ci = qidxL[t * 16 + j];
        const double ddx = Qx - (double)xb[ci];
        const double ddy = Qy - (double)xb[NPTS + ci];
        const double ddz = Qz - (double)xb[2 * NPTS + ci];
        const double dd = ddx * ddx + ddy * ddy + ddz * ddz;
        if (dd < d4 || (dd == d4 && ci < i4)) {
            if (dd < d3 || (dd == d3 && ci < i3)) {
                d4 = d3; i4 = i3;
                if (dd < d2 || (dd == d2 && ci < i2)) {
                    d3 = d2; i3 = i2;
                    if (dd < d1 || (dd == d1 && ci < i1)) {
                        d2 = d1; i2 = i1;
                        if (dd < d0 || (dd == d0 && ci < i0)) {
                            d1 = d0; i1 = i0; d0 = dd; i0 = ci;
                        } else { d1 = dd; i1 = ci; }
                    } else { d2 = dd; i2 = ci; }
                } else { d3 = dd; i3 = ci; }
            } else { d4 = dd; i4 = ci; }
        }
    }
    int* o = idx_out + ((size_t)b * NPTS + nq) * KNN;
    o[0] = i0; o[1] = i1; o[2] = i2; o[3] = i3; o[4] = i4;
}

// ---------------------------------------------------------------------------
// Kernel B1: gather + L1 (6->64) + x1max + L2 (64->64) + x2max (fp32 compute).
// ---------------------------------------------------------------------------
__global__ __launch_bounds__(256) void mlp12_kernel(const float* __restrict__ x,
                                                    const int* __restrict__ idx,
                                                    const float* __restrict__ w1,
                                                    const float* __restrict__ w2,
                                                    unsigned short* __restrict__ h2HL,
                                                    unsigned short* __restrict__ catH,
                                                    unsigned short* __restrict__ catL) {
    __shared__ float w1s[64 * 6];
    __shared__ float w2s[64 * 68];
    __shared__ float fbuf[80][6];
    __shared__ float h1s[80 * 68];
    __shared__ float h2s[80 * 68];
    const int t = threadIdx.x;
    const int pbase = blockIdx.x * 16;

    for (int i = t; i < 384; i += 256) w1s[i] = w1[i];
    for (int i = t; i < 4096; i += 256) {
        int c = i >> 6, q = i & 63;
        w2s[c * 68 + q] = w2[i];
    }
    if (t < 80) {
        const int pt = pbase + t / 5;
        const int b = pt >> 13;
        const int n = pt & 8191;
        const int k = t % 5;
        const int j = idx[(size_t)pt * KNN + k];
        const float* xb = x + (size_t)b * 3 * NPTS;
        fbuf[t][0] = xb[j];
        fbuf[t][1] = xb[NPTS + j];
        fbuf[t][2] = xb[2 * NPTS + j];
        fbuf[t][3] = xb[n];
        fbuf[t][4] = xb[NPTS + n];
        fbuf[t][5] = xb[2 * NPTS + n];
    }
    __syncthreads();

    for (int o = t; o < 5120; o += 256) {
        const int r = o >> 6, c = o & 63;
        float acc = 0.f;
        #pragma unroll
        for (int q = 0; q < 6; ++q) acc = fmaf(w1s[c * 6 + q], fbuf[r][q], acc);
        h1s[r * 68 + c] = fmaxf(acc, 0.f);
    }
    __syncthreads();

    for (int o = t; o < 1024; o += 256) {
        const int p = o >> 6, c = o & 63;
        float m = h1s[(p * 5) * 68 + c];
        #pragma unroll
        for (int k = 1; k < 5; ++k) m = fmaxf(m, h1s[(p * 5 + k) * 68 + c]);
        const unsigned short hi = f2bf(m);
        const size_t co = (size_t)(pbase + p) * 512 + c;
        catH[co] = hi;
        catL[co] = f2bf(m - bf2f(hi));
    }

    for (int tile = t; tile < 320; tile += 256) {
        const int r0 = (tile % 20) * 4;
        const int c0 = (tile / 20) * 4;
        float acc[4][4] = {};
        for (int q = 0; q < 64; q += 4) {
            float4 a[4], w[4];
            #pragma unroll
            for (int i = 0; i < 4; ++i) a[i] = *(const float4*)&h1s[(r0 + i) * 68 + q];
            #pragma unroll
            for (int j = 0; j < 4; ++j) w[j] = *(const float4*)&w2s[(c0 + j) * 68 + q];
            #pragma unroll
            for (int i = 0; i < 4; ++i)
                #pragma unroll
                for (int j = 0; j < 4; ++j) {
                    acc[i][j] = fmaf(a[i].x, w[j].x, acc[i][j]);
                    acc[i][j] = fmaf(a[i].y, w[j].y, acc[i][j]);
                    acc[i][j] = fmaf(a[i].z, w[j].z, acc[i][j]);
                    acc[i][j] = fmaf(a[i].w, w[j].w, acc[i][j]);
                }
        }
        #pragma unroll
        for (int i = 0; i < 4; ++i)
            #pragma unroll
            for (int j = 0; j < 4; ++j)
                h2s[(r0 + i) * 68 + c0 + j] = fmaxf(acc[i][j], 0.f);
    }
    __syncthreads();

    for (int o = t; o < 1024; o += 256) {
        const int p = o >> 6, c = o & 63;
        float m = h2s[(p * 5) * 68 + c];
        #pragma unroll
        for (int k = 1; k < 5; ++k) m = fmaxf(m, h2s[(p * 5 + k) * 68 + c]);
        const unsigned short hi = f2bf(m);
        const size_t co = (size_t)(pbase + p) * 512 + 64 + c;
        catH[co] = hi;
        catL[co] = f2bf(m - bf2f(hi));
    }
    for (int o = t; o < 5120; o += 256) {
        const int r = o >> 6, c = o & 63;
        const float v = h2s[r * 68 + c];
        const unsigned short hi = f2bf(v);
        const size_t rowb = (size_t)(pbase * 5 + r) * 128;
        h2HL[rowb + c]      = hi;
        h2HL[rowb + 64 + c] = f2bf(v - bf2f(hi));
    }
}

// ---------------------------------------------------------------------------
// Kernel B2: L3 (64->128) via split-bf16 MFMA + x3max.
// ---------------------------------------------------------------------------
__global__ __launch_bounds__(256) void mlp3_kernel(
        const unsigned short* __restrict__ h2HL,
        const unsigned short* __restrict__ w3H, const unsigned short* __restrict__ w3L,
        unsigned short* __restrict__ h3H, unsigned short* __restrict__ h3L,
        unsigned short* __restrict__ catH, unsigned short* __restrict__ catL) {
    __shared__ __align__(16) char smem[59904];
    unsigned short* aH = (unsigned short*)smem;            // [80][72]
    unsigned short* aL = aH + 80 * 72;                     // @11520B
    unsigned short* bH = (unsigned short*)(smem + 23040);  // [128][72]
    unsigned short* bL = (unsigned short*)(smem + 41472);

    const int t = threadIdx.x;
    const int R0 = blockIdx.x * 80;
    const int P0 = blockIdx.x * 16;

    for (int c = t; c < 1280; c += 256) {                  // A: h2 hi|lo rows
        const int row = c >> 4, seg = c & 15;
        const uint4 v = *(const uint4*)(h2HL + (size_t)(R0 + row) * 128 + seg * 8);
        *(uint4*)((seg < 8 ? aH : aL) + row * 72 + (seg & 7) * 8) = v;
    }
    for (int c = t; c < 1024; c += 256) {                  // B hi
        const int row = c >> 3, seg = c & 7;
        *(uint4*)(bH + row * 72 + seg * 8) =
            *(const uint4*)(w3H + row * 64 + seg * 8);
    }
    for (int c = t; c < 1024; c += 256) {                  // B lo
        const int row = c >> 3, seg = c & 7;
        *(uint4*)(bL + row * 72 + seg * 8) =
            *(const uint4*)(w3L + row * 64 + seg * 8);
    }
    __syncthreads();

    const int w = t >> 6, lane = t & 63;
    const int q = lane >> 4, l16 = lane & 15;
    const int n0 = w * 32;

    f32x4 acc[5][2];
    #pragma unroll
    for (int mt = 0; mt < 5; ++mt)
        #pragma unroll
        for (int nt = 0; nt < 2; ++nt)
            acc[mt][nt] = (f32x4){0.f, 0.f, 0.f, 0.f};

    #pragma unroll
    for (int kt = 0; kt < 2; ++kt) {
        const int k0 = kt * 32 + q * 8;
        bf16x8 bh[2], bl[2];
        #pragma unroll
        for (int nt = 0; nt < 2; ++nt) {
            bh[nt] = *(const bf16x8*)(bH + (n0 + nt * 16 + l16) * 72 + k0);
            bl[nt] = *(const bf16x8*)(bL + (n0 + nt * 16 + l16) * 72 + k0);
        }
        #pragma unroll
        for (int mt = 0; mt < 5; ++mt) {
            const bf16x8 ah = *(const bf16x8*)(aH + (mt * 16 + l16) * 72 + k0);
            const bf16x8 al = *(const bf16x8*)(aL + (mt * 16 + l16) * 72 + k0);
            #pragma unroll
            for (int nt = 0; nt < 2; ++nt) {
                acc[mt][nt] = MFMA16(ah, bh[nt], acc[mt][nt]);
                acc[mt][nt] = MFMA16(ah, bl[nt], acc[mt][nt]);
                acc[mt][nt] = MFMA16(al, bh[nt], acc[mt][nt]);
            }
        }
    }

    __syncthreads();                       // A/B staging dead; alias Dbuf
    float* Dbuf = (float*)smem;            // [80][132] fp32
    #pragma unroll
    for (int mt = 0; mt < 5; ++mt)
        #pragma unroll
        for (int nt = 0; nt < 2; ++nt)
            #pragma unroll
            for (int r = 0; r < 4; ++r)
                Dbuf[(mt * 16 + q * 4 + r) * 132 + n0 + nt * 16 + l16] =
                    fmaxf(acc[mt][nt][r], 0.f);
    __syncthreads();

    {
        const int col = t & 127;
        const int p0 = (t >> 7) * 8;
        #pragma unroll
        for (int p = 0; p < 8; ++p) {
            const int pp = p0 + p;
            float mx = 0.f;
            #pragma unroll
            for (int k = 0; k < 5; ++k) {
                const int row = pp * 5 + k;
                const float v = Dbuf[row * 132 + col];
                const unsigned short hi = f2bf(v);
                const unsigned short lo = f2bf(v - bf2f(hi));
                const size_t off = (size_t)(R0 + row) * 128 + col;
                h3H[off] = hi;
                h3L[off] = lo;
                mx = fmaxf(mx, bf2f(hi) + bf2f(lo));
            }
            const unsigned short mh = f2bf(mx);
            const size_t co = (size_t)(P0 + pp) * 512 + 128 + col;
            catH[co] = mh;
            catL[co] = f2bf(mx - bf2f(mh));
        }
    }
}

// ---------------------------------------------------------------------------
// Kernel C: L4 (128->256) via split-bf16 MFMA + x4max.
// ---------------------------------------------------------------------------
__global__ __launch_bounds__(256) void mlp4_kernel(
        const unsigned short* __restrict__ h3H, const unsigned short* __restrict__ h3L,
        const unsigned short* __restrict__ w4H, const unsigned short* __restrict__ w4L,
        unsigned short* __restrict__ catH, unsigned short* __restrict__ catL) {
    __shared__ __align__(16) char smem[64000];
    unsigned short* aH = (unsigned short*)smem;            // [80][136]
    unsigned short* aL = aH + 80 * 136;                    // @21760B
    unsigned short* bH = (unsigned short*)(smem + 43520);  // [128][40] per k-step
    unsigned short* bL = (unsigned short*)(smem + 53760);

    const int t = threadIdx.x;
    const int R0 = blockIdx.x * 80;
    const int P0 = blockIdx.x * 16;
    const int ny = blockIdx.y;                             // cout half

    for (int c = t; c < 1280; c += 256) {                  // A hi
        const int row = c >> 4, seg = c & 15;
        *(uint4*)(aH + row * 136 + seg * 8) =
            *(const uint4*)(h3H + (size_t)(R0 + row) * 128 + seg * 8);
    }
    for (int c = t; c < 1280; c += 256) {                  // A lo
        const int row = c >> 4, seg = c & 15;
        *(uint4*)(aL + row * 136 + seg * 8) =
            *(const uint4*)(h3L + (size_t)(R0 + row) * 128 + seg * 8);
    }

    const int w = t >> 6, lane = t & 63;
    const int q = lane >> 4, l16 = lane & 15;
    const int n0 = w * 32;

    f32x4 acc[5][2];
    #pragma unroll
    for (int mt = 0; mt < 5; ++mt)
        #pragma unroll
        for (int nt = 0; nt < 2; ++nt)
            acc[mt][nt] = (f32x4){0.f, 0.f, 0.f, 0.f};

    for (int ks = 0; ks < 4; ++ks) {
        __syncthreads();
        #pragma unroll
        for (int i = 0; i < 2; ++i) {                      // B hi: 512 chunks
            const int c = t + i * 256;
            const int row = c >> 2, seg = c & 3;
            *(uint4*)(bH + row * 40 + seg * 8) =
                *(const uint4*)(w4H + (size_t)(ny * 128 + row) * 128 + ks * 32 + seg * 8);
        }
        #pragma unroll
        for (int i = 0; i < 2; ++i) {                      // B lo
            const int c = t + i * 256;
            const int row = c >> 2, seg = c & 3;
            *(uint4*)(bL + row * 40 + seg * 8) =
                *(const uint4*)(w4L + (size_t)(ny * 128 + row) * 128 + ks * 32 + seg * 8);
        }
        __syncthreads();

        const int k0 = ks * 32 + q * 8;
        const int kb = q * 8;
        bf16x8 bh[2], bl[2];
        #pragma unroll
        for (int nt = 0; nt < 2; ++nt) {
            bh[nt] = *(const bf16x8*)(bH + (n0 + nt * 16 + l16) * 40 + kb);
            bl[nt] = *(const bf16x8*)(bL + (n0 + nt * 16 + l16) * 40 + kb);
        }
        #pragma unroll
        for (int mt = 0; mt < 5; ++mt) {
            const bf16x8 ah = *(const bf16x8*)(aH + (mt * 16 + l16) * 136 + k0);
            const bf16x8 al = *(const bf16x8*)(aL + (mt * 16 + l16) * 136 + k0);
            #pragma unroll
            for (int nt = 0; nt < 2; ++nt) {
                acc[mt][nt] = MFMA16(ah, bh[nt], acc[mt][nt]);
                acc[mt][nt] = MFMA16(ah, bl[nt], acc[mt][nt]);
                acc[mt][nt] = MFMA16(al, bh[nt], acc[mt][nt]);
            }
        }
    }

    __syncthreads();
    float* Dbuf = (float*)smem;            // [80][132] fp32
    #pragma unroll
    for (int mt = 0; mt < 5; ++mt)
        #pragma unroll
        for (int nt = 0; nt < 2; ++nt)
            #pragma unroll
            for (int r = 0; r < 4; ++r)
                Dbuf[(mt * 16 + q * 4 + r) * 132 + n0 + nt * 16 + l16] =
                    fmaxf(acc[mt][nt][r], 0.f);
    __syncthreads();

    {
        const int col = t & 127;
        const int p0 = (t >> 7) * 8;
        const int cout = 256 + ny * 128 + col;
        #pragma unroll
        for (int p = 0; p < 8; ++p) {
            const int pp = p0 + p;
            float mx = 0.f;
            #pragma unroll
            for (int k = 0; k < 5; ++k)
                mx = fmaxf(mx, Dbuf[(pp * 5 + k) * 132 + col]);
            const unsigned short mh = f2bf(mx);
            const size_t co = (size_t)(P0 + pp) * 512 + cout;
            catH[co] = mh;
            catL[co] = f2bf(mx - bf2f(mh));
        }
    }
}

// ---------------------------------------------------------------------------
// Kernel D: final GEMM out = relu(cat(32768x512) * W5^T) via split-bf16 MFMA.
// ---------------------------------------------------------------------------
__global__ __launch_bounds__(256) void gemm512_kernel(
        const unsigned short* __restrict__ catH, const unsigned short* __restrict__ catL,
        const unsigned short* __restrict__ w5H, const unsigned short* __restrict__ w5L,
        float* __restrict__ out) {
    __shared__ __align__(16) char smem[40960];
    unsigned short* aH = (unsigned short*)smem;            // [128][40]
    unsigned short* aL = aH + 128 * 40;                    // @10240B
    unsigned short* bH = (unsigned short*)(smem + 20480);
    unsigned short* bL = (unsigned short*)(smem + 30720);

    const int t = threadIdx.x;
    const int m0 = blockIdx.x * 128;
    const int n0blk = blockIdx.y * 128;

    const int w = t >> 6, lane = t & 63;
    const int q = lane >> 4, l16 = lane & 15;
    const int m_off = (w >> 1) * 64;
    const int n_off = (w & 1) * 64;

    f32x4 acc[4][4];
    #pragma unroll
    for (int mt = 0; mt < 4; ++mt)
        #pragma unroll
        for (int nt = 0; nt < 4; ++nt)
            acc[mt][nt] = (f32x4){0.f, 0.f, 0.f, 0.f};

    for (int kc = 0; kc < 512; kc += 32) {
        __syncthreads();
        #pragma unroll
        for (int i = 0; i < 2; ++i) {
            const int c = t + i * 256;
            const int row = c >> 2, seg = c & 3;
            *(uint4*)(aH + row * 40 + seg * 8) =
                *(const uint4*)(catH + (size_t)(m0 + row) * 512 + kc + seg * 8);
        }
        #pragma unroll
        for (int i = 0; i < 2; ++i) {
            const int c = t + i * 256;
            const int row = c >> 2, seg = c & 3;
            *(uint4*)(aL + row * 40 + seg * 8) =
                *(const uint4*)(catL + (size_t)(m0 + row) * 512 + kc + seg * 8);
        }
        #pragma unroll
        for (int i = 0; i < 2; ++i) {
            const int c = t + i * 256;
            const int row = c >> 2, seg = c & 3;
            *(uint4*)(bH + row * 40 + seg * 8) =
                *(const uint4*)(w5H + (size_t)(n0blk + row) * 512 + kc + seg * 8);
        }
        #pragma unroll
        for (int i = 0; i < 2; ++i) {
            const int c = t + i * 256;
            const int row = c >> 2, seg = c & 3;
            *(uint4*)(bL + row * 40 + seg * 8) =
                *(const uint4*)(w5L + (size_t)(n0blk + row) * 512 + kc + seg * 8);
        }
        __syncthreads();

        const int k0 = q * 8;
        bf16x8 bh[4], bl[4];
        #pragma unroll
        for (int nt = 0; nt < 4; ++nt) {
            bh[nt] = *(const bf16x8*)(bH + (n_off + nt * 16 + l16) * 40 + k0);
            bl[nt] = *(const bf16x8*)(bL + (n_off + nt * 16 + l16) * 40 + k0);
        }
        #pragma unroll
        for (int mt = 0; mt < 4; ++mt) {
            const bf16x8 ah = *(const bf16x8*)(aH + (m_off + mt * 16 + l16) * 40 + k0);
            const bf16x8 al = *(const bf16x8*)(aL + (m_off + mt * 16 + l16) * 40 + k0);
            #pragma unroll
            for (int nt = 0; nt < 4; ++nt) {
                acc[mt][nt] = MFMA16(ah, bh[nt], acc[mt][nt]);
                acc[mt][nt] = MFMA16(ah, bl[nt], acc[mt][nt]);
                acc[mt][nt] = MFMA16(al, bh[nt], acc[mt][nt]);
            }
        }
    }

    // band-wise epilogue: 8 bands of 16 rows; LDS transpose for coalesced out
    float* bandbuf = (float*)smem;         // [16][132] fp32
    for (int b8 = 0; b8 < 8; ++b8) {
        __syncthreads();
        if ((w >> 1) == (b8 >> 2)) {
            const int mt = b8 & 3;
            #pragma unroll
            for (int nt = 0; nt < 4; ++nt)
                #pragma unroll
                for (int r = 0; r < 4; ++r)
                    bandbuf[(q * 4 + r) * 132 + n_off + nt * 16 + l16] =
                        fmaxf(acc[mt][nt][r], 0.f);
        }
        __syncthreads();
        const int col = t >> 1;
        const int ph = (t & 1) * 8;
        const int P = m0 + b8 * 16 + ph;
        const int bb = P >> 13, nn = P & 8191;
        const int cout = n0blk + col;
        float tmp[8];
        #pragma unroll
        for (int j = 0; j < 8; ++j) tmp[j] = bandbuf[(ph + j) * 132 + col];
        float* op = &out[((size_t)bb * 512 + cout) * NPTS + nn];
        *(float4*)op       = make_float4(tmp[0], tmp[1], tmp[2], tmp[3]);
        *(float4*)(op + 4) = make_float4(tmp[4], tmp[5], tmp[6], tmp[7]);
    }
}

extern "C" void kernel_launch(void* const* d_in, const int* in_sizes, int n_in,
                              void* d_out, int out_size, void* d_ws, size_t ws_size,
                              hipStream_t stream) {
    (void)in_sizes; (void)n_in; (void)out_size; (void)ws_size;
    const float* x  = (const float*)d_in[0];
    const float* w1 = (const float*)d_in[1];
    const float* w2 = (const float*)d_in[2];
    const float* w3 = (const float*)d_in[3];
    const float* w4 = (const float*)d_in[4];
    const float* w5 = (const float*)d_in[5];
    float* out = (float*)d_out;

    // workspace layout (~113.4 MB total, < proven 145 MB)
    char* ws = (char*)d_ws;
    unsigned short* w3H = (unsigned short*)(ws + 0);          //  16384 B
    unsigned short* w3L = (unsigned short*)(ws + 16384);
    unsigned short* w4H = (unsigned short*)(ws + 32768);      //  65536 B
    unsigned short* w4L = (unsigned short*)(ws + 98304);
    unsigned short* w5H = (unsigned short*)(ws + 163840);     // 524288 B
    unsigned short* w5L = (unsigned short*)(ws + 688128);
    int*            idx = (int*)(ws + 1212416);               // 655360 B
    unsigned short* catH = (unsigned short*)(ws + 2097152);   // 33.55 MB
    unsigned short* catL = (unsigned short*)(ws + 35651584);  // 33.55 MB
    unsigned short* h3H  = (unsigned short*)(ws + 69206016);  // 41.94 MB
    // grid-KNN structures (after h3H @ 111149056)
    float*  bboxF      = (float*)(ws + 111149056);            //   128 B (pad 1K)
    int*    counts     = (int*)  (ws + 111150080);            // 512 KB
    int*    cell_cur   = (int*)  (ws + 111674368);            // 512 KB
    float4* sortedp    = (float4*)(ws + 112198656);           // 512 KB
    float4* tboxLo     = (float4*)(ws + 112723200);           //  32 KB
    float4* tboxHi     = (float4*)(ws + 112755968);           //  32 KB
    // d_out doubles as scratch: h2 (hi|lo interleaved) then h3L in-place
    unsigned short* h2HL = (unsigned short*)d_out;
    unsigned short* h3L  = (unsigned short*)d_out;

    wsplit_kernel<<<dim3(1184), dim3(256), 0, stream>>>(w3, w4, w5,
                                                        w3H, w3L, w4H, w4L, w5H, w5L);
    bbox_kernel<<<dim3(BATCH), dim3(1024), 0, stream>>>(x, bboxF, counts);
    count_kernel<<<dim3(128), dim3(256), 0, stream>>>(x, bboxF, counts);
    prefix_kernel<<<dim3(BATCH), dim3(1024), 0, stream>>>(counts, cell_cur);
    scatter_kernel<<<dim3(128), dim3(256), 0, stream>>>(x, bboxF, cell_cur, sortedp);
    tilebox_kernel<<<dim3(BATCH * NTILE / 4), dim3(256), 0, stream>>>(sortedp, tboxLo, tboxHi);
    knn_tile_kernel<<<dim3(128), dim3(256), 0, stream>>>(x, sortedp, tboxLo, tboxHi, idx);
    mlp12_kernel<<<dim3(BATCH * NPTS / 16), dim3(256), 0, stream>>>(x, idx, w1, w2,
                                                                    h2HL, catH, catL);
    mlp3_kernel<<<dim3(BATCH * NPTS * KNN / 80), dim3(256), 0, stream>>>(
        h2HL, w3H, w3L, h3H, h3L, catH, catL);
    mlp4_kernel<<<dim3(BATCH * NPTS * KNN / 80, 2), dim3(256), 0, stream>>>(
        h3H, h3L, w4H, w4L, catH, catL);
    gemm512_kernel<<<dim3(BATCH * NPTS / 128, 4), dim3(256), 0, stream>>>(
        catH, catL, w5H, w5L, out);
}

// Round 8
// 509.395 us; speedup vs baseline: 2.2134x; 2.2134x over previous
//
#include <hip/hip_runtime.h>
#include <cstdint>

#define BATCH 4
#define NPTS  8192
#define KNN   5
#define GRID  32
#define NCELL (GRID * GRID * GRID)
#define NTILE 128          // 8192/64 tiles per batch
#define CHUNK 32           // tiles staged per LDS pass
#define FCAP  24           // finalists per query

typedef short bf16x8 __attribute__((ext_vector_type(8)));
typedef float f32x4  __attribute__((ext_vector_type(4)));
#define MFMA16(a, b, c) __builtin_amdgcn_mfma_f32_16x16x32_bf16((a), (b), (c), 0, 0, 0)

__device__ __forceinline__ unsigned short f2bf(float x) {
    unsigned u = __float_as_uint(x);
    unsigned r = u + 0x7fffu + ((u >> 16) & 1u);   // RN-even
    return (unsigned short)(r >> 16);
}
__device__ __forceinline__ float bf2f(unsigned short h) {
    return __uint_as_float(((unsigned)h) << 16);
}

// monotone float <-> uint key (for atomic min/max)
__device__ __forceinline__ unsigned encf(float f) {
    int i = __float_as_int(f);
    return (unsigned)i ^ ((i >> 31) ? 0xFFFFFFFFu : 0x80000000u);
}
__device__ __forceinline__ float decf(unsigned k) {
    return __int_as_float((k & 0x80000000u) ? (int)(k ^ 0x80000000u) : (int)~k);
}

__device__ __forceinline__ int spread3(int v) {   // 5-bit -> every 3rd bit
    v &= 0x3ff;
    v = (v | (v << 16)) & 0x030000FF;
    v = (v | (v << 8))  & 0x0300F00F;
    v = (v | (v << 4))  & 0x030C30C3;
    v = (v | (v << 2))  & 0x09249249;
    return v;
}

// shared cell mapping (must be identical in count/scatter) -> MORTON code
__device__ __forceinline__ int cell_of(float px, float py, float pz,
                                       const float* __restrict__ bb) {
    const float ihx = (float)GRID / (bb[4] - bb[0]);
    const float ihy = (float)GRID / (bb[5] - bb[1]);
    const float ihz = (float)GRID / (bb[6] - bb[2]);
    const int cx = min(GRID - 1, max(0, (int)((px - bb[0]) * ihx)));
    const int cy = min(GRID - 1, max(0, (int)((py - bb[1]) * ihy)));
    const int cz = min(GRID - 1, max(0, (int)((pz - bb[2]) * ihz)));
    return spread3(cx) | (spread3(cy) << 1) | (spread3(cz) << 2);
}

__device__ __forceinline__ float wmaxf(float v) {
    #pragma unroll
    for (int m = 1; m < 64; m <<= 1) v = fmaxf(v, __shfl_xor(v, m));
    return v;
}

// ---------------------------------------------------------------------------
// Kernel W: split w3/w4/w5 into bf16 hi/lo pairs (fp32-emulation operands).
// ---------------------------------------------------------------------------
__global__ __launch_bounds__(256) void wsplit_kernel(
        const float* __restrict__ w3, const float* __restrict__ w4,
        const float* __restrict__ w5,
        unsigned short* __restrict__ w3H, unsigned short* __restrict__ w3L,
        unsigned short* __restrict__ w4H, unsigned short* __restrict__ w4L,
        unsigned short* __restrict__ w5H, unsigned short* __restrict__ w5L) {
    const int i = blockIdx.x * 256 + threadIdx.x;   // 303104 total, exact grid
    const float* src; unsigned short *dh, *dl; int off;
    if (i < 8192)       { src = w3; dh = w3H; dl = w3L; off = i; }
    else if (i < 40960) { src = w4; dh = w4H; dl = w4L; off = i - 8192; }
    else                { src = w5; dh = w5H; dl = w5L; off = i - 40960; }
    const float v = src[off];
    const unsigned short hi = f2bf(v);
    dh[off] = hi;
    dl[off] = f2bf(v - bf2f(hi));
}

// ---------------------------------------------------------------------------
// KNN build 1: per-batch bbox (padded) + zero the cell counters.
// ---------------------------------------------------------------------------
__global__ __launch_bounds__(1024) void bbox_kernel(const float* __restrict__ x,
                                                    float* __restrict__ bboxF,
                                                    int* __restrict__ counts) {
    __shared__ unsigned mnmx[6];
    const int b = blockIdx.x, t = threadIdx.x;
    if (t < 3) { mnmx[t] = 0xFFFFFFFFu; mnmx[3 + t] = 0u; }
    __syncthreads();
    const float* xb = x + (size_t)b * 3 * NPTS;
    #pragma unroll
    for (int a = 0; a < 3; ++a) {
        float lo = 3e38f, hi = -3e38f;
        for (int j = t; j < NPTS; j += 1024) {
            const float f = xb[a * NPTS + j];
            lo = fminf(lo, f); hi = fmaxf(hi, f);
        }
        atomicMin(&mnmx[a], encf(lo));
        atomicMax(&mnmx[3 + a], encf(hi));
    }
    __syncthreads();
    if (t < 3) {
        bboxF[b * 8 + t]     = decf(mnmx[t]) - 1e-3f;
        bboxF[b * 8 + 4 + t] = decf(mnmx[3 + t]) + 1e-3f;
    }
    int* cb = counts + b * NCELL;
    for (int j = t; j < NCELL; j += 1024) cb[j] = 0;
}

// ---------------------------------------------------------------------------
// KNN build 2: histogram points into morton cells.
// ---------------------------------------------------------------------------
__global__ __launch_bounds__(256) void count_kernel(const float* __restrict__ x,
                                                    const float* __restrict__ bboxF,
                                                    int* __restrict__ counts) {
    const int i = blockIdx.x * 256 + threadIdx.x;
    const int b = i >> 13, n = i & (NPTS - 1);
    const float* xb = x + (size_t)b * 3 * NPTS;
    const int c = cell_of(xb[n], xb[NPTS + n], xb[2 * NPTS + n], bboxF + b * 8);
    atomicAdd(&counts[b * NCELL + c], 1);
}

// ---------------------------------------------------------------------------
// KNN build 3: exclusive prefix over 32768 cells per batch (1 block).
// ---------------------------------------------------------------------------
__global__ __launch_bounds__(1024) void prefix_kernel(const int* __restrict__ counts,
                                                      int* __restrict__ cell_cur) {
    __shared__ int ssum[1024];
    const int b = blockIdx.x, t = threadIdx.x;
    const int* cb = counts + b * NCELL;
    int loc[32];
    int s = 0;
    #pragma unroll
    for (int j = 0; j < 32; ++j) { loc[j] = s; s += cb[t * 32 + j]; }
    ssum[t] = s;
    __syncthreads();
    for (int off = 1; off < 1024; off <<= 1) {
        const int v = (t >= off) ? ssum[t - off] : 0;
        __syncthreads();
        ssum[t] += v;
        __syncthreads();
    }
    const int base = ssum[t] - s;          // exclusive
    int* oc = cell_cur + b * NCELL;
    #pragma unroll
    for (int j = 0; j < 32; ++j) oc[t * 32 + j] = base + loc[j];
}

// ---------------------------------------------------------------------------
// KNN build 4: scatter points into morton-sorted order (orig idx in .w).
// ---------------------------------------------------------------------------
__global__ __launch_bounds__(256) void scatter_kernel(const float* __restrict__ x,
                                                      const float* __restrict__ bboxF,
                                                      int* __restrict__ cell_cur,
                                                      float4* __restrict__ sorted) {
    const int i = blockIdx.x * 256 + threadIdx.x;
    const int b = i >> 13, n = i & (NPTS - 1);
    const float* xb = x + (size_t)b * 3 * NPTS;
    const float px = xb[n], py = xb[NPTS + n], pz = xb[2 * NPTS + n];
    const int c = cell_of(px, py, pz, bboxF + b * 8);
    const int slot = atomicAdd(&cell_cur[b * NCELL + c], 1);
    sorted[(size_t)b * NPTS + slot] = make_float4(px, py, pz, __int_as_float(n));
}

// ---------------------------------------------------------------------------
// KNN build 5: per-tile bbox (64 consecutive sorted points), one wave/tile.
// ---------------------------------------------------------------------------
__global__ __launch_bounds__(256) void tilebox_kernel(const float4* __restrict__ sorted,
                                                      float4* __restrict__ tboxLo,
                                                      float4* __restrict__ tboxHi) {
    const int t = threadIdx.x, lane = t & 63, w = t >> 6;
    const int tile = blockIdx.x * 4 + w;           // 0..511 (B*NTILE)
    const float4 p = sorted[(size_t)tile * 64 + lane];
    float lx = p.x, ly = p.y, lz = p.z, hx = p.x, hy = p.y, hz = p.z;
    #pragma unroll
    for (int m = 1; m < 64; m <<= 1) {
        lx = fminf(lx, __shfl_xor(lx, m)); hx = fmaxf(hx, __shfl_xor(hx, m));
        ly = fminf(ly, __shfl_xor(ly, m)); hy = fmaxf(hy, __shfl_xor(hy, m));
        lz = fminf(lz, __shfl_xor(lz, m)); hz = fmaxf(hz, __shfl_xor(hz, m));
    }
    if (lane == 0) {
        tboxLo[tile] = make_float4(lx, ly, lz, 0.f);
        tboxHi[tile] = make_float4(hx, hy, hz, 0.f);
    }
}

// ---------------------------------------------------------------------------
// KNN query v6: 8-wave cooperative block per query tile (512 blocks, 4096
// waves = 4/SIMD). Phase A: wave 0 scans own tile -> thr0 = waveMax(5th)
// (upper bound on every query's true 5th: own tile has 64 >= 5 points).
// Phase B: bbox-filter all tiles vs thr0 (+2e-3 margin) -> LDS list.
// Phase C: chunk-stage <=32 tiles to LDS; candidates sliced DISJOINTLY
// across 8 waves; per-lane dual branchless fmed3 top-5 chains; float4
// LDS broadcast reads (wave-uniform, conflict-free). No duplicates ->
// exact fp32 5th of the scanned union. Phase D: 8-way chain merge per
// query -> T = 5th + 1e-4. Phase E: rescan own+list vs T, collect
// finalists (cap 24, LDS atomics). Phase F: exact fp64 rank-count re-rank
// ((d,idx) lexicographic = jax.lax.top_k tie semantics; HW-proven r5).
// ---------------------------------------------------------------------------
__global__ __launch_bounds__(512) void knn_tile2_kernel(
        const float* __restrict__ x, const float4* __restrict__ sorted,
        const float4* __restrict__ tboxLo, const float4* __restrict__ tboxHi,
        int* __restrict__ idx_out) {
    __shared__ __align__(16) char sm[52744];
    float4* cand  = (float4*)sm;                 // [2048] 32KB (aliased w/ mrg)
    float*  mrg   = (float*)sm;                  // [64*80] 20KB alias
    int*    tlist = (int*)(sm + 32768);          // [128]
    int*    nlist = (int*)(sm + 33280);
    float*  thr0s = (float*)(sm + 33284);
    float*  Tq    = (float*)(sm + 33288);        // [64]
    int*    qcnt  = (int*)(sm + 33544);          // [64]
    int*    nqA   = (int*)(sm + 33800);          // [64]
    int*    qidx  = (int*)(sm + 34056);          // [64*FCAP] 6144B
    double* qd    = (double*)(sm + 40200);       // [64*FCAP] 12288B (8-aligned)

    const int t = threadIdx.x, lane = t & 63, w = t >> 6;
    const int g = blockIdx.x;              // 0..511
    const int b = g >> 7, t0 = g & (NTILE - 1);
    const float4* sp = sorted + (size_t)b * NPTS;
    const float4* tlo = tboxLo + (size_t)b * NTILE;
    const float4* thi = tboxHi + (size_t)b * NTILE;
    const float* xb = x + (size_t)b * 3 * NPTS;

    if (t == 0) *nlist = 0;
    if (t < 64) qcnt[t] = 0;

    const float4 qp = sp[t0 * 64 + lane];
    const float qx = qp.x, qy = qp.y, qz = qp.z;
    if (w == 0) nqA[lane] = __float_as_int(qp.w);

    auto dist2 = [&](const float4 v) {
        const float dx = qx - v.x, dy = qy - v.y, dz = qz - v.z;
        return fmaf(dz, dz, fmaf(dy, dy, dx * dx));
    };

    float a0 = 3e38f, a1 = 3e38f, a2 = 3e38f, a3 = 3e38f, a4 = 3e38f;
    float b0 = 3e38f, b1 = 3e38f, b2 = 3e38f, b3 = 3e38f, b4 = 3e38f;
    auto insA = [&](float d) {
        a4 = __builtin_amdgcn_fmed3f(a3, d, a4);
        a3 = __builtin_amdgcn_fmed3f(a2, d, a3);
        a2 = __builtin_amdgcn_fmed3f(a1, d, a2);
        a1 = __builtin_amdgcn_fmed3f(a0, d, a1);
        a0 = fminf(a0, d);
    };
    auto insB = [&](float d) {
        b4 = __builtin_amdgcn_fmed3f(b3, d, b4);
        b3 = __builtin_amdgcn_fmed3f(b2, d, b3);
        b2 = __builtin_amdgcn_fmed3f(b1, d, b2);
        b1 = __builtin_amdgcn_fmed3f(b0, d, b1);
        b0 = fminf(b0, d);
    };
    auto u5 = [&]() {   // 5th smallest of union of the two sorted chains
        return fminf(fminf(fminf(a4, b4), fminf(fmaxf(a0, b3), fmaxf(a1, b2))),
                     fminf(fmaxf(a2, b1), fmaxf(a3, b0)));
    };

    // stage own tile
    if (t < 64) cand[t] = sp[t0 * 64 + t];
    __syncthreads();

    // ---- phase A: wave 0 scans own tile -> thr0 ----
    if (w == 0) {
        #pragma unroll 4
        for (int j = 0; j < 64; j += 2) {
            insA(dist2(cand[j]));
            insB(dist2(cand[j + 1]));
        }
        const float th = wmaxf(u5());
        if (lane == 0) *thr0s = th;
    }
    __syncthreads();
    const float thrL = *thr0s + 2e-3f;

    // ---- phase B: bbox-filter tiles ----
    const float4 wlo = tlo[t0], whi = thi[t0];
    if (t < NTILE && t != t0) {
        const float4 lo = tlo[t], hi = thi[t];
        const float dx = fmaxf(0.f, fmaxf(lo.x - whi.x, wlo.x - hi.x));
        const float dy = fmaxf(0.f, fmaxf(lo.y - whi.y, wlo.y - hi.y));
        const float dz = fmaxf(0.f, fmaxf(lo.z - whi.z, wlo.z - hi.z));
        if (fmaf(dz, dz, fmaf(dy, dy, dx * dx)) <= thrL) {
            const int s = atomicAdd(nlist, 1);
            tlist[s] = t;
        }
    }
    __syncthreads();
    const int NL = *nlist;

    // ---- phase C: chunked sliced scan (no duplicates: wave0 has own tile) ----
    for (int base = 0; base < NL; base += CHUNK) {
        const int nt = min(CHUNK, NL - base);
        __syncthreads();
        for (int i = t; i < nt * 64; i += 512)
            cand[i] = sp[tlist[base + (i >> 6)] * 64 + (i & 63)];
        __syncthreads();
        const int nc = nt * 64;
        const int per = (nc + 7) >> 3;
        const int lo = w * per, hi2 = min(nc, lo + per);
        int j = lo;
        for (; j + 1 < hi2; j += 2) {
            insA(dist2(cand[j]));
            insB(dist2(cand[j + 1]));
        }
        if (j < hi2) insA(dist2(cand[j]));
    }

    // ---- phase D: merge the 8 per-wave chains per query ----
    __syncthreads();                       // cand reads done; alias mrg
    {
        float* m = &mrg[lane * 80 + w * 10];
        m[0] = a0; m[1] = a1; m[2] = a2; m[3] = a3; m[4] = a4;
        m[5] = b0; m[6] = b1; m[7] = b2; m[8] = b3; m[9] = b4;
    }
    __syncthreads();
    if (t < 64) {
        float s0 = 3e38f, s1 = 3e38f, s2 = 3e38f, s3 = 3e38f, s4 = 3e38f;
        #pragma unroll 10
        for (int j = 0; j < 80; ++j) {
            const float d = mrg[t * 80 + j];
            s4 = __builtin_amdgcn_fmed3f(s3, d, s4);
            s3 = __builtin_amdgcn_fmed3f(s2, d, s3);
            s2 = __builtin_amdgcn_fmed3f(s1, d, s2);
            s1 = __builtin_amdgcn_fmed3f(s0, d, s1);
            s0 = fminf(s0, d);
        }
        Tq[t] = s4 + 1e-4f;
    }
    __syncthreads();
    const float Tl = Tq[lane];

    // ---- phase E: finalist collection (own tile + list, sliced) ----
    if (t < 64) cand[t] = sp[t0 * 64 + t];     // restage own tile (mrg clobbered)
    __syncthreads();
    for (int j = w * 8; j < w * 8 + 8; ++j) {  // own tile: 8 cands per wave
        const float4 v = cand[j];
        if (dist2(v) < Tl) {
            const int s = atomicAdd(&qcnt[lane], 1);
            if (s < FCAP) qidx[lane * FCAP + s] = __float_as_int(v.w);
        }
    }
    for (int base = 0; base < NL; base += CHUNK) {
        const int nt = min(CHUNK, NL - base);
        __syncthreads();
        for (int i = t; i < nt * 64; i += 512)
            cand[i] = sp[tlist[base + (i >> 6)] * 64 + (i & 63)];
        __syncthreads();
        const int nc = nt * 64;
        const int per = (nc + 7) >> 3;
        const int lo = w * per, hi2 = min(nc, lo + per);
        for (int j = lo; j < hi2; ++j) {
            const float4 v = cand[j];
            if (dist2(v) < Tl) {
                const int s = atomicAdd(&qcnt[lane], 1);
                if (s < FCAP) qidx[lane * FCAP + s] = __float_as_int(v.w);
            }
        }
    }
    __syncthreads();

    // ---- phase F: exact fp64 rank-count top-5 (8 threads/query) ----
    const int ql = t >> 3, jt = t & 7;
    const int cnt = min(qcnt[ql], FCAP);
    const int nqq = nqA[ql];
    const double Qx = (double)xb[nqq];
    const double Qy = (double)xb[NPTS + nqq];
    const double Qz = (double)xb[2 * NPTS + nqq];
    for (int j = jt; j < cnt; j += 8) {
        const int ci = qidx[ql * FCAP + j];
        const double ddx = Qx - (double)xb[ci];
        const double ddy = Qy - (double)xb[NPTS + ci];
        const double ddz = Qz - (double)xb[2 * NPTS + ci];
        qd[ql * FCAP + j] = ddx * ddx + ddy * ddy + ddz * ddz;
    }
    __syncthreads();
    for (int j = jt; j < cnt; j += 8) {
        const double dj = qd[ql * FCAP + j];
        const int    ij = qidx[ql * FCAP + j];
        int rank = 0;
        for (int k = 0; k < cnt; ++k) {
            const double dk = qd[ql * FCAP + k];
            const int    ik = qidx[ql * FCAP + k];
            rank += (dk < dj) || (dk == dj && ik < ij);
        }
        if (rank < KNN)
            idx_out[((size_t)b * NPTS + nqq) * KNN + rank] = ij;
    }
}

// ---------------------------------------------------------------------------
// Kernel B1: gather + L1 (6->64) + x1max + L2 (64->64) + x2max (fp32 compute).
// ---------------------------------------------------------------------------
__global__ __launch_bounds__(256) void mlp12_kernel(const float* __restrict__ x,
                                                    const int* __restrict__ idx,
                                                    const float* __restrict__ w1,
                                                    const float* __restrict__ w2,
                                                    unsigned short* __restrict__ h2HL,
                                                    unsigned short* __restrict__ catH,
                                                    unsigned short* __restrict__ catL) {
    __shared__ float w1s[64 * 6];
    __shared__ float w2s[64 * 68];
    __shared__ float fbuf[80][6];
    __shared__ float h1s[80 * 68];
    __shared__ float h2s[80 * 68];
    const int t = threadIdx.x;
    const int pbase = blockIdx.x * 16;

    for (int i = t; i < 384; i += 256) w1s[i] = w1[i];
    for (int i = t; i < 4096; i += 256) {
        int c = i >> 6, q = i & 63;
        w2s[c * 68 + q] = w2[i];
    }
    if (t < 80) {
        const int pt = pbase + t / 5;
        const int b = pt >> 13;
        const int n = pt & 8191;
        const int k = t % 5;
        const int j = idx[(size_t)pt * KNN + k];
        const float* xb = x + (size_t)b * 3 * NPTS;
        fbuf[t][0] = xb[j];
        fbuf[t][1] = xb[NPTS + j];
        fbuf[t][2] = xb[2 * NPTS + j];
        fbuf[t][3] = xb[n];
        fbuf[t][4] = xb[NPTS + n];
        fbuf[t][5] = xb[2 * NPTS + n];
    }
    __syncthreads();

    for (int o = t; o < 5120; o += 256) {
        const int r = o >> 6, c = o & 63;
        float acc = 0.f;
        #pragma unroll
        for (int q = 0; q < 6; ++q) acc = fmaf(w1s[c * 6 + q], fbuf[r][q], acc);
        h1s[r * 68 + c] = fmaxf(acc, 0.f);
    }
    __syncthreads();

    for (int o = t; o < 1024; o += 256) {
        const int p = o >> 6, c = o & 63;
        float m = h1s[(p * 5) * 68 + c];
        #pragma unroll
        for (int k = 1; k < 5; ++k) m = fmaxf(m, h1s[(p * 5 + k) * 68 + c]);
        const unsigned short hi = f2bf(m);
        const size_t co = (size_t)(pbase + p) * 512 + c;
        catH[co] = hi;
        catL[co] = f2bf(m - bf2f(hi));
    }

    for (int tile = t; tile < 320; tile += 256) {
        const int r0 = (tile % 20) * 4;
        const int c0 = (tile / 20) * 4;
        float acc[4][4] = {};
        for (int q = 0; q < 64; q += 4) {
            float4 a[4], w[4];
            #pragma unroll
            for (int i = 0; i < 4; ++i) a[i] = *(const float4*)&h1s[(r0 + i) * 68 + q];
            #pragma unroll
            for (int j = 0; j < 4; ++j) w[j] = *(const float4*)&w2s[(c0 + j) * 68 + q];
            #pragma unroll
            for (int i = 0; i < 4; ++i)
                #pragma unroll
                for (int j = 0; j < 4; ++j) {
                    acc[i][j] = fmaf(a[i].x, w[j].x, acc[i][j]);
                    acc[i][j] = fmaf(a[i].y, w[j].y, acc[i][j]);
                    acc[i][j] = fmaf(a[i].z, w[j].z, acc[i][j]);
                    acc[i][j] = fmaf(a[i].w, w[j].w, acc[i][j]);
                }
        }
        #pragma unroll
        for (int i = 0; i < 4; ++i)
            #pragma unroll
            for (int j = 0; j < 4; ++j)
                h2s[(r0 + i) * 68 + c0 + j] = fmaxf(acc[i][j], 0.f);
    }
    __syncthreads();

    for (int o = t; o < 1024; o += 256) {
        const int p = o >> 6, c = o & 63;
        float m = h2s[(p * 5) * 68 + c];
        #pragma unroll
        for (int k = 1; k < 5; ++k) m = fmaxf(m, h2s[(p * 5 + k) * 68 + c]);
        const unsigned short hi = f2bf(m);
        const size_t co = (size_t)(pbase + p) * 512 + 64 + c;
        catH[co] = hi;
        catL[co] = f2bf(m - bf2f(hi));
    }
    for (int o = t; o < 5120; o += 256) {
        const int r = o >> 6, c = o & 63;
        const float v = h2s[r * 68 + c];
        const unsigned short hi = f2bf(v);
        const size_t rowb = (size_t)(pbase * 5 + r) * 128;
        h2HL[rowb + c]      = hi;
        h2HL[rowb + 64 + c] = f2bf(v - bf2f(hi));
    }
}

// ---------------------------------------------------------------------------
// Kernel B2: L3 (64->128) via split-bf16 MFMA + x3max.
// ---------------------------------------------------------------------------
__global__ __launch_bounds__(256) void mlp3_kernel(
        const unsigned short* __restrict__ h2HL,
        const unsigned short* __restrict__ w3H, const unsigned short* __restrict__ w3L,
        unsigned short* __restrict__ h3H, unsigned short* __restrict__ h3L,
        unsigned short* __restrict__ catH, unsigned short* __restrict__ catL) {
    __shared__ __align__(16) char smem[59904];
    unsigned short* aH = (unsigned short*)smem;            // [80][72]
    unsigned short* aL = aH + 80 * 72;                     // @11520B
    unsigned short* bH = (unsigned short*)(smem + 23040);  // [128][72]
    unsigned short* bL = (unsigned short*)(smem + 41472);

    const int t = threadIdx.x;
    const int R0 = blockIdx.x * 80;
    const int P0 = blockIdx.x * 16;

    for (int c = t; c < 1280; c += 256) {                  // A: h2 hi|lo rows
        const int row = c >> 4, seg = c & 15;
        const uint4 v = *(const uint4*)(h2HL + (size_t)(R0 + row) * 128 + seg * 8);
        *(uint4*)((seg < 8 ? aH : aL) + row * 72 + (seg & 7) * 8) = v;
    }
    for (int c = t; c < 1024; c += 256) {                  // B hi
        const int row = c >> 3, seg = c & 7;
        *(uint4*)(bH + row * 72 + seg * 8) =
            *(const uint4*)(w3H + row * 64 + seg * 8);
    }
    for (int c = t; c < 1024; c += 256) {                  // B lo
        const int row = c >> 3, seg = c & 7;
        *(uint4*)(bL + row * 72 + seg * 8) =
            *(const uint4*)(w3L + row * 64 + seg * 8);
    }
    __syncthreads();

    const int w = t >> 6, lane = t & 63;
    const int q = lane >> 4, l16 = lane & 15;
    const int n0 = w * 32;

    f32x4 acc[5][2];
    #pragma unroll
    for (int mt = 0; mt < 5; ++mt)
        #pragma unroll
        for (int nt = 0; nt < 2; ++nt)
            acc[mt][nt] = (f32x4){0.f, 0.f, 0.f, 0.f};

    #pragma unroll
    for (int kt = 0; kt < 2; ++kt) {
        const int k0 = kt * 32 + q * 8;
        bf16x8 bh[2], bl[2];
        #pragma unroll
        for (int nt = 0; nt < 2; ++nt) {
            bh[nt] = *(const bf16x8*)(bH + (n0 + nt * 16 + l16) * 72 + k0);
            bl[nt] = *(const bf16x8*)(bL + (n0 + nt * 16 + l16) * 72 + k0);
        }
        #pragma unroll
        for (int mt = 0; mt < 5; ++mt) {
            const bf16x8 ah = *(const bf16x8*)(aH + (mt * 16 + l16) * 72 + k0);
            const bf16x8 al = *(const bf16x8*)(aL + (mt * 16 + l16) * 72 + k0);
            #pragma unroll
            for (int nt = 0; nt < 2; ++nt) {
                acc[mt][nt] = MFMA16(ah, bh[nt], acc[mt][nt]);
                acc[mt][nt] = MFMA16(ah, bl[nt], acc[mt][nt]);
                acc[mt][nt] = MFMA16(al, bh[nt], acc[mt][nt]);
            }
        }
    }

    __syncthreads();                       // A/B staging dead; alias Dbuf
    float* Dbuf = (float*)smem;            // [80][132] fp32
    #pragma unroll
    for (int mt = 0; mt < 5; ++mt)
        #pragma unroll
        for (int nt = 0; nt < 2; ++nt)
            #pragma unroll
            for (int r = 0; r < 4; ++r)
                Dbuf[(mt * 16 + q * 4 + r) * 132 + n0 + nt * 16 + l16] =
                    fmaxf(acc[mt][nt][r], 0.f);
    __syncthreads();

    {
        const int col = t & 127;
        const int p0 = (t >> 7) * 8;
        #pragma unroll
        for (int p = 0; p < 8; ++p) {
            const int pp = p0 + p;
            float mx = 0.f;
            #pragma unroll
            for (int k = 0; k < 5; ++k) {
                const int row = pp * 5 + k;
                const float v = Dbuf[row * 132 + col];
                const unsigned short hi = f2bf(v);
                const unsigned short lo = f2bf(v - bf2f(hi));
                const size_t off = (size_t)(R0 + row) * 128 + col;
                h3H[off] = hi;
                h3L[off] = lo;
                mx = fmaxf(mx, bf2f(hi) + bf2f(lo));
            }
            const unsigned short mh = f2bf(mx);
            const size_t co = (size_t)(P0 + pp) * 512 + 128 + col;
            catH[co] = mh;
            catL[co] = f2bf(mx - bf2f(mh));
        }
    }
}

// ---------------------------------------------------------------------------
// Kernel C: L4 (128->256) via split-bf16 MFMA + x4max.
// ---------------------------------------------------------------------------
__global__ __launch_bounds__(256) void mlp4_kernel(
        const unsigned short* __restrict__ h3H, const unsigned short* __restrict__ h3L,
        const unsigned short* __restrict__ w4H, const unsigned short* __restrict__ w4L,
        unsigned short* __restrict__ catH, unsigned short* __restrict__ catL) {
    __shared__ __align__(16) char smem[64000];
    unsigned short* aH = (unsigned short*)smem;            // [80][136]
    unsigned short* aL = aH + 80 * 136;                    // @21760B
    unsigned short* bH = (unsigned short*)(smem + 43520);  // [128][40] per k-step
    unsigned short* bL = (unsigned short*)(smem + 53760);

    const int t = threadIdx.x;
    const int R0 = blockIdx.x * 80;
    const int P0 = blockIdx.x * 16;
    const int ny = blockIdx.y;                             // cout half

    for (int c = t; c < 1280; c += 256) {                  // A hi
        const int row = c >> 4, seg = c & 15;
        *(uint4*)(aH + row * 136 + seg * 8) =
            *(const uint4*)(h3H + (size_t)(R0 + row) * 128 + seg * 8);
    }
    for (int c = t; c < 1280; c += 256) {                  // A lo
        const int row = c >> 4, seg = c & 15;
        *(uint4*)(aL + row * 136 + seg * 8) =
            *(const uint4*)(h3L + (size_t)(R0 + row) * 128 + seg * 8);
    }

    const int w = t >> 6, lane = t & 63;
    const int q = lane >> 4, l16 = lane & 15;
    const int n0 = w * 32;

    f32x4 acc[5][2];
    #pragma unroll
    for (int mt = 0; mt < 5; ++mt)
        #pragma unroll
        for (int nt = 0; nt < 2; ++nt)
            acc[mt][nt] = (f32x4){0.f, 0.f, 0.f, 0.f};

    for (int ks = 0; ks < 4; ++ks) {
        __syncthreads();
        #pragma unroll
        for (int i = 0; i < 2; ++i) {                      // B hi: 512 chunks
            const int c = t + i * 256;
            const int row = c >> 2, seg = c & 3;
            *(uint4*)(bH + row * 40 + seg * 8) =
                *(const uint4*)(w4H + (size_t)(ny * 128 + row) * 128 + ks * 32 + seg * 8);
        }
        #pragma unroll
        for (int i = 0; i < 2; ++i) {                      // B lo
            const int c = t + i * 256;
            const int row = c >> 2, seg = c & 3;
            *(uint4*)(bL + row * 40 + seg * 8) =
                *(const uint4*)(w4L + (size_t)(ny * 128 + row) * 128 + ks * 32 + seg * 8);
        }
        __syncthreads();

        const int k0 = ks * 32 + q * 8;
        const int kb = q * 8;
        bf16x8 bh[2], bl[2];
        #pragma unroll
        for (int nt = 0; nt < 2; ++nt) {
            bh[nt] = *(const bf16x8*)(bH + (n0 + nt * 16 + l16) * 40 + kb);
            bl[nt] = *(const bf16x8*)(bL + (n0 + nt * 16 + l16) * 40 + kb);
        }
        #pragma unroll
        for (int mt = 0; mt < 5; ++mt) {
            const bf16x8 ah = *(const bf16x8*)(aH + (mt * 16 + l16) * 136 + k0);
            const bf16x8 al = *(const bf16x8*)(aL + (mt * 16 + l16) * 136 + k0);
            #pragma unroll
            for (int nt = 0; nt < 2; ++nt) {
                acc[mt][nt] = MFMA16(ah, bh[nt], acc[mt][nt]);
                acc[mt][nt] = MFMA16(ah, bl[nt], acc[mt][nt]);
                acc[mt][nt] = MFMA16(al, bh[nt], acc[mt][nt]);
            }
        }
    }

    __syncthreads();
    float* Dbuf = (float*)smem;            // [80][132] fp32
    #pragma unroll
    for (int mt = 0; mt < 5; ++mt)
        #pragma unroll
        for (int nt = 0; nt < 2; ++nt)
            #pragma unroll
            for (int r = 0; r < 4; ++r)
                Dbuf[(mt * 16 + q * 4 + r) * 132 + n0 + nt * 16 + l16] =
                    fmaxf(acc[mt][nt][r], 0.f);
    __syncthreads();

    {
        const int col = t & 127;
        const int p0 = (t >> 7) * 8;
        const int cout = 256 + ny * 128 + col;
        #pragma unroll
        for (int p = 0; p < 8; ++p) {
            const int pp = p0 + p;
            float mx = 0.f;
            #pragma unroll
            for (int k = 0; k < 5; ++k)
                mx = fmaxf(mx, Dbuf[(pp * 5 + k) * 132 + col]);
            const unsigned short mh = f2bf(mx);
            const size_t co = (size_t)(P0 + pp) * 512 + cout;
            catH[co] = mh;
            catL[co] = f2bf(mx - bf2f(mh));
        }
    }
}

// ---------------------------------------------------------------------------
// Kernel D: final GEMM out = relu(cat(32768x512) * W5^T) via split-bf16 MFMA.
// ---------------------------------------------------------------------------
__global__ __launch_bounds__(256) void gemm512_kernel(
        const unsigned short* __restrict__ catH, const unsigned short* __restrict__ catL,
        const unsigned short* __restrict__ w5H, const unsigned short* __restrict__ w5L,
        float* __restrict__ out) {
    __shared__ __align__(16) char smem[40960];
    unsigned short* aH = (unsigned short*)smem;            // [128][40]
    unsigned short* aL = aH + 128 * 40;                    // @10240B
    unsigned short* bH = (unsigned short*)(smem + 20480);
    unsigned short* bL = (unsigned short*)(smem + 30720);

    const int t = threadIdx.x;
    const int m0 = blockIdx.x * 128;
    const int n0blk = blockIdx.y * 128;

    const int w = t >> 6, lane = t & 63;
    const int q = lane >> 4, l16 = lane & 15;
    const int m_off = (w >> 1) * 64;
    const int n_off = (w & 1) * 64;

    f32x4 acc[4][4];
    #pragma unroll
    for (int mt = 0; mt < 4; ++mt)
        #pragma unroll
        for (int nt = 0; nt < 4; ++nt)
            acc[mt][nt] = (f32x4){0.f, 0.f, 0.f, 0.f};

    for (int kc = 0; kc < 512; kc += 32) {
        __syncthreads();
        #pragma unroll
        for (int i = 0; i < 2; ++i) {
            const int c = t + i * 256;
            const int row = c >> 2, seg = c & 3;
            *(uint4*)(aH + row * 40 + seg * 8) =
                *(const uint4*)(catH + (size_t)(m0 + row) * 512 + kc + seg * 8);
        }
        #pragma unroll
        for (int i = 0; i < 2; ++i) {
            const int c = t + i * 256;
            const int row = c >> 2, seg = c & 3;
            *(uint4*)(aL + row * 40 + seg * 8) =
                *(const uint4*)(catL + (size_t)(m0 + row) * 512 + kc + seg * 8);
        }
        #pragma unroll
        for (int i = 0; i < 2; ++i) {
            const int c = t + i * 256;
            const int row = c >> 2, seg = c & 3;
            *(uint4*)(bH + row * 40 + seg * 8) =
                *(const uint4*)(w5H + (size_t)(n0blk + row) * 512 + kc + seg * 8);
        }
        #pragma unroll
        for (int i = 0; i < 2; ++i) {
            const int c = t + i * 256;
            const int row = c >> 2, seg = c & 3;
            *(uint4*)(bL + row * 40 + seg * 8) =
                *(const uint4*)(w5L + (size_t)(n0blk + row) * 512 + kc + seg * 8);
        }
        __syncthreads();

        const int k0 = q * 8;
        bf16x8 bh[4], bl[4];
        #pragma unroll
        for (int nt = 0; nt < 4; ++nt) {
            bh[nt] = *(const bf16x8*)(bH + (n_off + nt * 16 + l16) * 40 + k0);
            bl[nt] = *(const bf16x8*)(bL + (n_off + nt * 16 + l16) * 40 + k0);
        }
        #pragma unroll
        for (int mt = 0; mt < 4; ++mt) {
            const bf16x8 ah = *(const bf16x8*)(aH + (m_off + mt * 16 + l16) * 40 + k0);
            const bf16x8 al = *(const bf16x8*)(aL + (m_off + mt * 16 + l16) * 40 + k0);
            #pragma unroll
            for (int nt = 0; nt < 4; ++nt) {
                acc[mt][nt] = MFMA16(ah, bh[nt], acc[mt][nt]);
                acc[mt][nt] = MFMA16(ah, bl[nt], acc[mt][nt]);
                acc[mt][nt] = MFMA16(al, bh[nt], acc[mt][nt]);
            }
        }
    }

    // band-wise epilogue: 8 bands of 16 rows; LDS transpose for coalesced out
    float* bandbuf = (float*)smem;         // [16][132] fp32
    for (int b8 = 0; b8 < 8; ++b8) {
        __syncthreads();
        if ((w >> 1) == (b8 >> 2)) {
            const int mt = b8 & 3;
            #pragma unroll
            for (int nt = 0; nt < 4; ++nt)
                #pragma unroll
                for (int r = 0; r < 4; ++r)
                    bandbuf[(q * 4 + r) * 132 + n_off + nt * 16 + l16] =
                        fmaxf(acc[mt][nt][r], 0.f);
        }
        __syncthreads();
        const int col = t >> 1;
        const int ph = (t & 1) * 8;
        const int P = m0 + b8 * 16 + ph;
        const int bb = P >> 13, nn = P & 8191;
        const int cout = n0blk + col;
        float tmp[8];
        #pragma unroll
        for (int j = 0; j < 8; ++j) tmp[j] = bandbuf[(ph + j) * 132 + col];
        float* op = &out[((size_t)bb * 512 + cout) * NPTS + nn];
        *(float4*)op       = make_float4(tmp[0], tmp[1], tmp[2], tmp[3]);
        *(float4*)(op + 4) = make_float4(tmp[4], tmp[5], tmp[6], tmp[7]);
    }
}

extern "C" void kernel_launch(void* const* d_in, const int* in_sizes, int n_in,
                              void* d_out, int out_size, void* d_ws, size_t ws_size,
                              hipStream_t stream) {
    (void)in_sizes; (void)n_in; (void)out_size; (void)ws_size;
    const float* x  = (const float*)d_in[0];
    const float* w1 = (const float*)d_in[1];
    const float* w2 = (const float*)d_in[2];
    const float* w3 = (const float*)d_in[3];
    const float* w4 = (const float*)d_in[4];
    const float* w5 = (const float*)d_in[5];
    float* out = (float*)d_out;

    // workspace layout (~113.4 MB total, < proven 145 MB)
    char* ws = (char*)d_ws;
    unsigned short* w3H = (unsigned short*)(ws + 0);          //  16384 B
    unsigned short* w3L = (unsigned short*)(ws + 16384);
    unsigned short* w4H = (unsigned short*)(ws + 32768);      //  65536 B
    unsigned short* w4L = (unsigned short*)(ws + 98304);
    unsigned short* w5H = (unsigned short*)(ws + 163840);     // 524288 B
    unsigned short* w5L = (unsigned short*)(ws + 688128);
    int*            idx = (int*)(ws + 1212416);               // 655360 B
    unsigned short* catH = (unsigned short*)(ws + 2097152);   // 33.55 MB
    unsigned short* catL = (unsigned short*)(ws + 35651584);  // 33.55 MB
    unsigned short* h3H  = (unsigned short*)(ws + 69206016);  // 41.94 MB
    // grid-KNN structures (after h3H @ 111149056)
    float*  bboxF      = (float*)(ws + 111149056);            //   128 B (pad 1K)
    int*    counts     = (int*)  (ws + 111150080);            // 512 KB
    int*    cell_cur   = (int*)  (ws + 111674368);            // 512 KB
    float4* sortedp    = (float4*)(ws + 112198656);           // 512 KB
    float4* tboxLo     = (float4*)(ws + 112723200);           //  32 KB
    float4* tboxHi     = (float4*)(ws + 112755968);           //  32 KB
    // d_out doubles as scratch: h2 (hi|lo interleaved) then h3L in-place
    unsigned short* h2HL = (unsigned short*)d_out;
    unsigned short* h3L  = (unsigned short*)d_out;

    wsplit_kernel<<<dim3(1184), dim3(256), 0, stream>>>(w3, w4, w5,
                                                        w3H, w3L, w4H, w4L, w5H, w5L);
    bbox_kernel<<<dim3(BATCH), dim3(1024), 0, stream>>>(x, bboxF, counts);
    count_kernel<<<dim3(128), dim3(256), 0, stream>>>(x, bboxF, counts);
    prefix_kernel<<<dim3(BATCH), dim3(1024), 0, stream>>>(counts, cell_cur);
    scatter_kernel<<<dim3(128), dim3(256), 0, stream>>>(x, bboxF, cell_cur, sortedp);
    tilebox_kernel<<<dim3(BATCH * NTILE / 4), dim3(256), 0, stream>>>(sortedp, tboxLo, tboxHi);
    knn_tile2_kernel<<<dim3(BATCH * NTILE), dim3(512), 0, stream>>>(
        x, sortedp, tboxLo, tboxHi, idx);
    mlp12_kernel<<<dim3(BATCH * NPTS / 16), dim3(256), 0, stream>>>(x, idx, w1, w2,
                                                                    h2HL, catH, catL);
    mlp3_kernel<<<dim3(BATCH * NPTS * KNN / 80), dim3(256), 0, stream>>>(
        h2HL, w3H, w3L, h3H, h3L, catH, catL);
    mlp4_kernel<<<dim3(BATCH * NPTS * KNN / 80, 2), dim3(256), 0, stream>>>(
        h3H, h3L, w4H, w4L, catH, catL);
    gemm512_kernel<<<dim3(BATCH * NPTS / 128, 4), dim3(256), 0, stream>>>(
        catH, catL, w5H, w5L, out);
}